// Round 4
// baseline (317.503 us; speedup 1.0000x reference)
//
#include <hip/hip_runtime.h>
#include <hip/hip_bf16.h>
#include <math.h>

#define Bn 8
#define Ln 512
#define Dn 768
#define NHn 12
#define DHn 64
#define K1n 20
#define K2n 20

// workspace layout (bytes)
#define WS_ACC    0          // double acc[8]: [0]=pair_num [1]=trip_num [2]=trip_cnt
#define WS_GSCORE 64         // float g_score[8*512]
#define WS_LOCR   16448      // float loc_rows[8*20*512] (320 KB)
#define WS_GTOP   344128     // int g_top[8*20]
#define WS_LTOP   344768     // int l_top[8*20*20]
#define WS_SBF    357568     // ushort sbf[8*12*512*64] bf16 head-major
#define WS_TBF    6649024    // ushort tbf[...] (ends 12940480)
#define WS_ZERO_BYTES 344128 // acc + g_score + loc_rows

typedef __attribute__((ext_vector_type(8))) short bf16x8;
typedef __attribute__((ext_vector_type(4))) float f32x4;

__device__ inline unsigned short f2bf(float x) {
  __hip_bfloat16 h = __float2bfloat16(x);
  return *reinterpret_cast<unsigned short*>(&h);
}
__device__ inline float bf2f(unsigned short u) {
  return __uint_as_float(((unsigned int)u) << 16);
}

// ---------------------------------------------------------------------------
// Prep: fp32 [b][row][h*64+k] -> bf16 head-major [b][h][row][k]
// ---------------------------------------------------------------------------
__global__ __launch_bounds__(256) void prep_bf16_kernel(
    const float* __restrict__ s, const float* __restrict__ t,
    unsigned short* __restrict__ sbf, unsigned short* __restrict__ tbf) {
  int gid = blockIdx.x * 256 + threadIdx.x;
  int f = gid * 4;
  int col = f % Dn;
  int rb = f / Dn;
  int row = rb & (Ln - 1);
  int b = rb >> 9;
  int h = col >> 6;
  int k = col & 63;
  size_t dst = (((size_t)(b * NHn + h) * Ln + row) * DHn + k);
  float4 vs = *(const float4*)(s + f);
  float4 vt = *(const float4*)(t + f);
  ushort4 us, ut;
  us.x = f2bf(vs.x); us.y = f2bf(vs.y); us.z = f2bf(vs.z); us.w = f2bf(vs.w);
  ut.x = f2bf(vt.x); ut.y = f2bf(vt.y); ut.z = f2bf(vt.z); ut.w = f2bf(vt.w);
  *(ushort4*)(sbf + dst) = us;
  *(ushort4*)(tbf + dst) = ut;
}

// ---------------------------------------------------------------------------
// Kernel A: one block per (b, h, 64-row tile). diff^2 + t-softmax column sums
// (g_score) with e-values deferred in registers (packed bf16). NO loc write.
// ---------------------------------------------------------------------------
__global__ __launch_bounds__(512, 4) void pairA_kernel(
    const unsigned short* __restrict__ sbf, const unsigned short* __restrict__ tbf,
    const float* __restrict__ mask, float* __restrict__ g_score,
    double* __restrict__ acc) {
  const int b = blockIdx.x & 7;
  const int r = blockIdx.x >> 3;          // 0..95
  const int it = r / NHn;                 // 0..7
  const int h = r - it * NHn;             // 0..11
  const int i0 = it * 64;
  const int tid = threadIdx.x;
  const int w = tid >> 6;                 // 0..7
  const int lane = tid & 63;
  const int lr = lane & 15, lg = lane >> 4;
  const int rw = (w >> 1) * 16;           // row group: 0,16,32,48
  const int cw = (w & 1) * 256;           // col half

  __shared__ float Mcol[Ln];
  __shared__ float gcol[Ln];
  __shared__ float redsum[2][64];
  __shared__ float wred[8];

  for (int j = tid; j < Ln; j += 512) {
    Mcol[j] = mask[b * Ln + j];
    gcol[j] = 0.0f;
  }
  __syncthreads();

  const size_t hb = (size_t)(b * NHn + h) * Ln;
  const unsigned short* pas = sbf + (hb + i0 + rw + lr) * DHn + lg * 8;
  const unsigned short* pat = tbf + (hb + i0 + rw + lr) * DHn + lg * 8;
  bf16x8 sa0 = *(const bf16x8*)pas;
  bf16x8 sa1 = *(const bf16x8*)(pas + 32);
  bf16x8 ta0 = *(const bf16x8*)pat;
  bf16x8 ta1 = *(const bf16x8*)(pat + 32);
  float mrow[4];
  #pragma unroll
  for (int q = 0; q < 4; ++q) mrow[q] = mask[b * Ln + i0 + rw + lg * 4 + q];

  const f32x4 zero4 = {0.0f, 0.0f, 0.0f, 0.0f};
  float lpair = 0.0f;
  float rsum[4] = {0.0f, 0.0f, 0.0f, 0.0f};
  unsigned int epack[32];                  // deferred e values, packed bf16

  #pragma unroll
  for (int ct = 0; ct < 16; ++ct) {
    const int j0 = cw + ct * 16;
    const unsigned short* pbs = sbf + (hb + j0 + lr) * DHn + lg * 8;
    const unsigned short* pbt = tbf + (hb + j0 + lr) * DHn + lg * 8;
    bf16x8 sb0 = *(const bf16x8*)pbs;
    bf16x8 sb1 = *(const bf16x8*)(pbs + 32);
    bf16x8 tb0 = *(const bf16x8*)pbt;
    bf16x8 tb1 = *(const bf16x8*)(pbt + 32);
    f32x4 sacc = __builtin_amdgcn_mfma_f32_16x16x32_bf16(sa0, sb0, zero4, 0, 0, 0);
    sacc = __builtin_amdgcn_mfma_f32_16x16x32_bf16(sa1, sb1, sacc, 0, 0, 0);
    f32x4 tacc = __builtin_amdgcn_mfma_f32_16x16x32_bf16(ta0, tb0, zero4, 0, 0, 0);
    tacc = __builtin_amdgcn_mfma_f32_16x16x32_bf16(ta1, tb1, tacc, 0, 0, 0);
    const float mj = Mcol[j0 + lr];
    float e4[4];
    #pragma unroll
    for (int q = 0; q < 4; ++q) {
      const float mm = mrow[q] * mj;
      const float ss = sacc[q] * 0.125f * mm;
      const float st = tacc[q] * 0.125f * mm;
      const float d = ss - st;
      lpair += d * d;
      const float e = __expf(st + (1.0f - mm) * (-10000.0f));
      rsum[q] += e;
      e4[q] = e;
    }
    epack[ct * 2]     = (unsigned int)f2bf(e4[0]) | ((unsigned int)f2bf(e4[1]) << 16);
    epack[ct * 2 + 1] = (unsigned int)f2bf(e4[2]) | ((unsigned int)f2bf(e4[3]) << 16);
  }

  // row-sum: reduce over the 16 lr lanes, then across the wave pair (col halves)
  #pragma unroll
  for (int o = 1; o < 16; o <<= 1) {
    #pragma unroll
    for (int q = 0; q < 4; ++q) rsum[q] += __shfl_xor(rsum[q], o, 64);
  }
  if (lr == 0) {
    #pragma unroll
    for (int q = 0; q < 4; ++q) redsum[w & 1][rw + lg * 4 + q] = rsum[q];
  }
  __syncthreads();
  float rscale[4];
  #pragma unroll
  for (int q = 0; q < 4; ++q) {
    const int ri = rw + lg * 4 + q;
    rscale[q] = mrow[q] / fmaxf(redsum[0][ri] + redsum[1][ri], 1e-30f);
  }

  // column partial sums of att = e * rscale; reduce over lg groups in-wave
  float pc[16];
  #pragma unroll
  for (int ct = 0; ct < 16; ++ct) {
    const float e0 = __uint_as_float(epack[ct * 2] << 16);
    const float e1 = __uint_as_float(epack[ct * 2] & 0xffff0000u);
    const float e2 = __uint_as_float(epack[ct * 2 + 1] << 16);
    const float e3 = __uint_as_float(epack[ct * 2 + 1] & 0xffff0000u);
    pc[ct] = e0 * rscale[0] + e1 * rscale[1] + e2 * rscale[2] + e3 * rscale[3];
  }
  #pragma unroll
  for (int o = 16; o < 64; o <<= 1) {
    #pragma unroll
    for (int ct = 0; ct < 16; ++ct) pc[ct] += __shfl_xor(pc[ct], o, 64);
  }
  if (lg == 0) {
    #pragma unroll
    for (int ct = 0; ct < 16; ++ct)
      atomicAdd(&gcol[cw + ct * 16 + lr], pc[ct]);   // LDS pre-reduction
  }

  // pair-loss partial
  #pragma unroll
  for (int o = 1; o < 64; o <<= 1) lpair += __shfl_xor(lpair, o, 64);
  if (lane == 0) wred[w] = lpair;
  __syncthreads();

  if (tid == 0) {
    float s = 0.0f;
    #pragma unroll
    for (int i = 0; i < 8; ++i) s += wred[i];
    atomicAdd(&acc[0], (double)s);
  }
  {
    const int j = tid;
    if (j < Ln) atomicAdd(&g_score[b * Ln + j], gcol[j] * Mcol[j]);
  }
}

// ---------------------------------------------------------------------------
// top-k over g_score: single-wave register argmax (tie -> lowest index)
// ---------------------------------------------------------------------------
__global__ __launch_bounds__(64) void topk_g_kernel(
    const float* __restrict__ g_score, int* __restrict__ g_top) {
  const int b = blockIdx.x, lane = threadIdx.x;
  float v[8];
  #pragma unroll
  for (int q = 0; q < 8; ++q) v[q] = g_score[b * Ln + q * 64 + lane];
  for (int r = 0; r < K1n; ++r) {
    float bv = v[0]; int bq = 0;
    #pragma unroll
    for (int q = 1; q < 8; ++q) if (v[q] > bv) { bv = v[q]; bq = q; }
    int bj = bq * 64 + lane;
    #pragma unroll
    for (int o = 1; o < 64; o <<= 1) {
      float ov = __shfl_xor(bv, o, 64);
      int oj = __shfl_xor(bj, o, 64);
      if (ov > bv || (ov == bv && oj < bj)) { bv = ov; bj = oj; }
    }
    if (lane == 0) g_top[b * K1n + r] = bj;
    const int wq = bj >> 6, wl = bj & 63;
    #pragma unroll
    for (int q = 0; q < 8; ++q)
      if (q == wq && lane == wl) v[q] = -3.0e38f;
  }
}

// ---------------------------------------------------------------------------
// Kernel B: recompute att rows only for g_top rows; accumulate over h into
// loc_rows[b][i1][j]. One block per (b, h) = 96 blocks.
// ---------------------------------------------------------------------------
__global__ __launch_bounds__(256, 4) void pairB_kernel(
    const unsigned short* __restrict__ tbf, const float* __restrict__ mask,
    const int* __restrict__ g_top, float* __restrict__ loc_rows) {
  const int b = blockIdx.x & 7;
  const int h = blockIdx.x >> 3;
  const int tid = threadIdx.x;
  const int w = tid >> 6, lane = tid & 63;
  const int lr = lane & 15, lg = lane >> 4;
  const int cw = w * 128;

  __shared__ int gidx[32];
  __shared__ float mrow_s[32];
  __shared__ float rscale_s[32];
  __shared__ float redsum[4][32];
  __shared__ float McolB[Ln];
  __shared__ unsigned short es[32][Ln + 8];

  if (tid < 32) {
    const int gi = (tid < K1n) ? g_top[b * K1n + tid] : 0;
    gidx[tid] = gi;
    mrow_s[tid] = (tid < K1n) ? mask[b * Ln + gi] : 0.0f;
  }
  for (int j = tid; j < Ln; j += 256) McolB[j] = mask[b * Ln + j];
  __syncthreads();

  const size_t hb = (size_t)(b * NHn + h) * Ln;
  bf16x8 ta[2][2];
  #pragma unroll
  for (int rt = 0; rt < 2; ++rt) {
    const unsigned short* p = tbf + (hb + gidx[rt * 16 + lr]) * DHn + lg * 8;
    ta[rt][0] = *(const bf16x8*)p;
    ta[rt][1] = *(const bf16x8*)(p + 32);
  }
  const f32x4 zero4 = {0.0f, 0.0f, 0.0f, 0.0f};
  float rsum[2][4] = {{0, 0, 0, 0}, {0, 0, 0, 0}};
  #pragma unroll
  for (int ct = 0; ct < 8; ++ct) {
    const int j0 = cw + ct * 16;
    const unsigned short* pb = tbf + (hb + j0 + lr) * DHn + lg * 8;
    bf16x8 tb0 = *(const bf16x8*)pb;
    bf16x8 tb1 = *(const bf16x8*)(pb + 32);
    const float mj = McolB[j0 + lr];
    #pragma unroll
    for (int rt = 0; rt < 2; ++rt) {
      f32x4 tacc = __builtin_amdgcn_mfma_f32_16x16x32_bf16(ta[rt][0], tb0, zero4, 0, 0, 0);
      tacc = __builtin_amdgcn_mfma_f32_16x16x32_bf16(ta[rt][1], tb1, tacc, 0, 0, 0);
      #pragma unroll
      for (int q = 0; q < 4; ++q) {
        const int ri = rt * 16 + lg * 4 + q;
        const float mm = mrow_s[ri] * mj;
        const float st = tacc[q] * 0.125f * mm;
        const float e = __expf(st + (1.0f - mm) * (-10000.0f));
        rsum[rt][q] += e;
        es[ri][j0 + lr] = f2bf(e);
      }
    }
  }
  #pragma unroll
  for (int o = 1; o < 16; o <<= 1) {
    #pragma unroll
    for (int rt = 0; rt < 2; ++rt)
      #pragma unroll
      for (int q = 0; q < 4; ++q) rsum[rt][q] += __shfl_xor(rsum[rt][q], o, 64);
  }
  if (lr == 0) {
    #pragma unroll
    for (int rt = 0; rt < 2; ++rt)
      #pragma unroll
      for (int q = 0; q < 4; ++q) redsum[w][rt * 16 + lg * 4 + q] = rsum[rt][q];
  }
  __syncthreads();
  if (tid < 32) {
    const float fs = redsum[0][tid] + redsum[1][tid] + redsum[2][tid] + redsum[3][tid];
    rscale_s[tid] = mrow_s[tid] / fmaxf(fs, 1e-30f);
  }
  __syncthreads();
  for (int idx = tid; idx < K1n * Ln; idx += 256) {
    const int ri = idx >> 9, j = idx & (Ln - 1);
    const float e = bf2f(es[ri][j]);
    atomicAdd(&loc_rows[(size_t)(b * K1n + ri) * Ln + j], e * rscale_s[ri] * McolB[j]);
  }
}

// ---------------------------------------------------------------------------
// top-k over loc rows (diagonal zeroed): single-wave register argmax
// ---------------------------------------------------------------------------
__global__ __launch_bounds__(64) void topk_l_kernel(
    const float* __restrict__ loc_rows, const int* __restrict__ g_top,
    int* __restrict__ l_top) {
  const int blk = blockIdx.x, lane = threadIdx.x;
  const int b = blk / K1n, i1 = blk % K1n;
  const int g = g_top[b * K1n + i1];
  const float* r0 = loc_rows + (size_t)(b * K1n + i1) * Ln;
  float v[8];
  #pragma unroll
  for (int q = 0; q < 8; ++q) {
    const int j = q * 64 + lane;
    v[q] = (j == g) ? 0.0f : r0[j];
  }
  for (int r = 0; r < K2n; ++r) {
    float bv = v[0]; int bq = 0;
    #pragma unroll
    for (int q = 1; q < 8; ++q) if (v[q] > bv) { bv = v[q]; bq = q; }
    int bj = bq * 64 + lane;
    #pragma unroll
    for (int o = 1; o < 64; o <<= 1) {
      float ov = __shfl_xor(bv, o, 64);
      int oj = __shfl_xor(bj, o, 64);
      if (ov > bv || (ov == bv && oj < bj)) { bv = ov; bj = oj; }
    }
    if (lane == 0) l_top[(b * K1n + i1) * K2n + r] = bj;
    const int wq = bj >> 6, wl = bj & 63;
    #pragma unroll
    for (int q = 0; q < 8; ++q)
      if (q == wq && lane == wl) v[q] = -3.0e38f;
  }
}

// ---------------------------------------------------------------------------
// Triplet loss: normalized diffs (fp32 math) -> bf16 LDS; 20x20 Gram via MFMA
// (one 16x16 quadrant per wave). One block per (b, i1).
// ---------------------------------------------------------------------------
#define TP (Dn + 16)

__global__ __launch_bounds__(256, 1) void triplet_kernel(
    const float* __restrict__ s_rep, const float* __restrict__ t_rep,
    const float* __restrict__ mask, const int* __restrict__ g_top,
    const int* __restrict__ l_top, double* __restrict__ acc) {
  const int blk = blockIdx.x, tid = threadIdx.x;
  const int b = blk / K1n, i1 = blk % K1n;
  const int w = tid >> 6, lane = tid & 63;
  const int lr = lane & 15, lg = lane >> 4;

  __shared__ unsigned short NS[32][TP];
  __shared__ unsigned short NT[32][TP];
  __shared__ int lidx[K2n];
  __shared__ float fl2[K2n];
  __shared__ float sred[4], cred[4];

  const int g = g_top[b * K1n + i1];
  if (tid < K2n) {
    const int li = l_top[(b * K1n + i1) * K2n + tid];
    lidx[tid] = li;
    fl2[tid] = (mask[b * Ln + g] + mask[b * Ln + li] == 2.0f) ? 1.0f : 0.0f;
  }
  __syncthreads();

  const float* pgs = s_rep + (size_t)(b * Ln + g) * Dn;
  const float* pgt = t_rep + (size_t)(b * Ln + g) * Dn;
  for (int j = w; j < K2n; j += 4) {
    const float* pls = s_rep + (size_t)(b * Ln + lidx[j]) * Dn;
    const float* plt = t_rep + (size_t)(b * Ln + lidx[j]) * Dn;
    float4 ds[3], dt[3];
    float ssq = 0.0f, tsq = 0.0f;
    #pragma unroll
    for (int q = 0; q < 3; ++q) {
      const int c = lane * 4 + q * 256;
      float4 a = *(const float4*)&pgs[c];
      float4 x = *(const float4*)&pls[c];
      ds[q] = make_float4(a.x - x.x, a.y - x.y, a.z - x.z, a.w - x.w);
      ssq += ds[q].x * ds[q].x + ds[q].y * ds[q].y + ds[q].z * ds[q].z + ds[q].w * ds[q].w;
      float4 c2 = *(const float4*)&pgt[c];
      float4 y = *(const float4*)&plt[c];
      dt[q] = make_float4(c2.x - y.x, c2.y - y.y, c2.z - y.z, c2.w - y.w);
      tsq += dt[q].x * dt[q].x + dt[q].y * dt[q].y + dt[q].z * dt[q].z + dt[q].w * dt[q].w;
    }
    #pragma unroll
    for (int o = 1; o < 64; o <<= 1) {
      ssq += __shfl_xor(ssq, o, 64);
      tsq += __shfl_xor(tsq, o, 64);
    }
    const float sinv = 1.0f / fmaxf(sqrtf(ssq), 1e-12f);
    const float tinv = 1.0f / fmaxf(sqrtf(tsq), 1e-12f);
    #pragma unroll
    for (int q = 0; q < 3; ++q) {
      const int c = lane * 4 + q * 256;
      ushort4 us, ut;
      us.x = f2bf(ds[q].x * sinv); us.y = f2bf(ds[q].y * sinv);
      us.z = f2bf(ds[q].z * sinv); us.w = f2bf(ds[q].w * sinv);
      ut.x = f2bf(dt[q].x * tinv); ut.y = f2bf(dt[q].y * tinv);
      ut.z = f2bf(dt[q].z * tinv); ut.w = f2bf(dt[q].w * tinv);
      *(ushort4*)&NS[j][c] = us;
      *(ushort4*)&NT[j][c] = ut;
    }
  }
  __syncthreads();

  // Gram quadrant per wave: rows qr*16.., cols qc*16..
  const int qr = w >> 1, qc = w & 1;
  f32x4 sacc = {0.0f, 0.0f, 0.0f, 0.0f};
  f32x4 tacc = {0.0f, 0.0f, 0.0f, 0.0f};
  #pragma unroll
  for (int ks = 0; ks < 24; ++ks) {
    const int kk = ks * 32 + lg * 8;
    bf16x8 as = *(const bf16x8*)&NS[qr * 16 + lr][kk];
    bf16x8 bs = *(const bf16x8*)&NS[qc * 16 + lr][kk];
    bf16x8 at = *(const bf16x8*)&NT[qr * 16 + lr][kk];
    bf16x8 bt = *(const bf16x8*)&NT[qc * 16 + lr][kk];
    sacc = __builtin_amdgcn_mfma_f32_16x16x32_bf16(as, bs, sacc, 0, 0, 0);
    tacc = __builtin_amdgcn_mfma_f32_16x16x32_bf16(at, bt, tacc, 0, 0, 0);
  }
  float psum = 0.0f, pcnt = 0.0f;
  #pragma unroll
  for (int q = 0; q < 4; ++q) {
    const int j2 = qr * 16 + lg * 4 + q;    // Gram row
    const int k2 = qc * 16 + lr;            // Gram col
    if (j2 < K2n && k2 < K2n && j2 != k2) {
      const float am = fl2[j2] * fl2[k2];
      const bool smv = (am != 0.0f) && (sacc[q] != 0.0f);
      const bool tmv = (am != 0.0f) && (tacc[q] != 0.0f);
      const float sv = smv ? sacc[q] : 0.0f;
      const float tv = tmv ? tacc[q] : 0.0f;
      const float d = sv - tv;
      const float ad = fabsf(d);
      psum += (ad < 1.0f) ? 0.5f * d * d : (ad - 0.5f);
      pcnt += smv ? 1.0f : 0.0f;
    }
  }
  #pragma unroll
  for (int o = 1; o < 64; o <<= 1) {
    psum += __shfl_xor(psum, o, 64);
    pcnt += __shfl_xor(pcnt, o, 64);
  }
  if (lane == 0) { sred[w] = psum; cred[w] = pcnt; }
  __syncthreads();
  if (tid == 0) {
    atomicAdd(&acc[1], (double)(sred[0] + sred[1] + sred[2] + sred[3]));
    atomicAdd(&acc[2], (double)(cred[0] + cred[1] + cred[2] + cred[3]));
  }
}

// ---------------------------------------------------------------------------
// Finalize: sum(mext) = sum_b (sum_i m)^2; combine losses.
// ---------------------------------------------------------------------------
__global__ void finalize_kernel(const float* __restrict__ mask,
                                const double* __restrict__ acc, float* __restrict__ out) {
  int tid = threadIdx.x;
  __shared__ float red[4];
  double sm = 0.0;
  for (int b = 0; b < Bn; ++b) {
    float p = 0.0f;
    for (int i = tid; i < Ln; i += 256) p += mask[b * Ln + i];
    #pragma unroll
    for (int o = 1; o < 64; o <<= 1) p += __shfl_xor(p, o, 64);
    __syncthreads();
    if ((tid & 63) == 0) red[tid >> 6] = p;
    __syncthreads();
    if (tid == 0) {
      float rs = red[0] + red[1] + red[2] + red[3];
      sm += (double)rs * (double)rs;
    }
  }
  __syncthreads();
  if (tid == 0) {
    double lp = acc[0] / ((double)NHn * sm);
    double lt = acc[1] / acc[2];
    out[0] = (float)(lp + lt);
  }
}

// ---------------------------------------------------------------------------
extern "C" void kernel_launch(void* const* d_in, const int* in_sizes, int n_in,
                              void* d_out, int out_size, void* d_ws, size_t ws_size,
                              hipStream_t stream) {
  const float* s_rep = (const float*)d_in[0];
  const float* t_rep = (const float*)d_in[1];
  const float* mask  = (const float*)d_in[2];
  float* out = (float*)d_out;

  char* w = (char*)d_ws;
  double* acc      = (double*)(w + WS_ACC);
  float* g_score   = (float*)(w + WS_GSCORE);
  float* loc_rows  = (float*)(w + WS_LOCR);
  int* g_top       = (int*)(w + WS_GTOP);
  int* l_top       = (int*)(w + WS_LTOP);
  unsigned short* sbf = (unsigned short*)(w + WS_SBF);
  unsigned short* tbf = (unsigned short*)(w + WS_TBF);

  hipMemsetAsync(d_ws, 0, WS_ZERO_BYTES, stream);

  prep_bf16_kernel<<<Bn * Ln * Dn / 4 / 256, 256, 0, stream>>>(s_rep, t_rep, sbf, tbf);
  pairA_kernel<<<Bn * NHn * (Ln / 64), 512, 0, stream>>>(sbf, tbf, mask, g_score, acc);
  topk_g_kernel<<<Bn, 64, 0, stream>>>(g_score, g_top);
  pairB_kernel<<<Bn * NHn, 256, 0, stream>>>(tbf, mask, g_top, loc_rows);
  topk_l_kernel<<<Bn * K1n, 64, 0, stream>>>(loc_rows, g_top, l_top);
  triplet_kernel<<<Bn * K1n, 256, 0, stream>>>(s_rep, t_rep, mask, g_top, l_top, acc);
  finalize_kernel<<<1, 256, 0, stream>>>(mask, acc, out);
}

// Round 5
// 195.313 us; speedup vs baseline: 1.6256x; 1.6256x over previous
//
#include <hip/hip_runtime.h>
#include <hip/hip_bf16.h>
#include <math.h>

#define Bn 8
#define Ln 512
#define Dn 768
#define NHn 12
#define DHn 64
#define K1n 20
#define K2n 20

// workspace layout (bytes)
#define WS_ACC    0          // double acc[8]: [0]=pair_num [1]=trip_num [2]=trip_cnt
#define WS_GSCORE 64         // float g_score[8*512]
#define WS_LOCR   16448      // float loc_rows[8*20*512] (320 KB)
#define WS_GTOP   344128     // int g_top[8*20]
#define WS_LTOP   344768     // int l_top[8*20*20]
#define WS_SBF    357568     // ushort sbf[8*12*512*64] bf16 head-major
#define WS_TBF    6649024    // ushort tbf[...] (ends 12940480)
#define WS_ZERO_BYTES 344128 // acc + g_score + loc_rows

typedef __attribute__((ext_vector_type(8))) short bf16x8;
typedef __attribute__((ext_vector_type(4))) float f32x4;

__device__ inline unsigned short f2bf(float x) {
  __hip_bfloat16 h = __float2bfloat16(x);
  return *reinterpret_cast<unsigned short*>(&h);
}
__device__ inline float bf2f(unsigned short u) {
  return __uint_as_float(((unsigned int)u) << 16);
}

// ---------------------------------------------------------------------------
// Prep: fp32 [b][row][h*64+k] -> bf16 head-major [b][h][row][k]
// ---------------------------------------------------------------------------
__global__ __launch_bounds__(256) void prep_bf16_kernel(
    const float* __restrict__ s, const float* __restrict__ t,
    unsigned short* __restrict__ sbf, unsigned short* __restrict__ tbf) {
  int gid = blockIdx.x * 256 + threadIdx.x;
  int f = gid * 4;
  int col = f % Dn;
  int rb = f / Dn;
  int row = rb & (Ln - 1);
  int b = rb >> 9;
  int h = col >> 6;
  int k = col & 63;
  size_t dst = (((size_t)(b * NHn + h) * Ln + row) * DHn + k);
  float4 vs = *(const float4*)(s + f);
  float4 vt = *(const float4*)(t + f);
  ushort4 us, ut;
  us.x = f2bf(vs.x); us.y = f2bf(vs.y); us.z = f2bf(vs.z); us.w = f2bf(vs.w);
  ut.x = f2bf(vt.x); ut.y = f2bf(vt.y); ut.z = f2bf(vt.z); ut.w = f2bf(vt.w);
  *(ushort4*)(sbf + dst) = us;
  *(ushort4*)(tbf + dst) = ut;
}

// ---------------------------------------------------------------------------
// Kernel A: one block per (b, h, 64-row tile). diff^2 + t-softmax column sums
// (g_score) with e-values deferred in registers (packed bf16). NO loc write.
// __launch_bounds__(512, 2): 128-VGPR cap -- the kernel needs ~110 live regs;
// the (512,4)/64-VGPR variant spilled 485 MB of scratch per dispatch (round 4).
// ---------------------------------------------------------------------------
__global__ __launch_bounds__(512, 2) void pairA_kernel(
    const unsigned short* __restrict__ sbf, const unsigned short* __restrict__ tbf,
    const float* __restrict__ mask, float* __restrict__ g_score,
    double* __restrict__ acc) {
  const int b = blockIdx.x & 7;
  const int r = blockIdx.x >> 3;          // 0..95
  const int it = r / NHn;                 // 0..7
  const int h = r - it * NHn;             // 0..11
  const int i0 = it * 64;
  const int tid = threadIdx.x;
  const int w = tid >> 6;                 // 0..7
  const int lane = tid & 63;
  const int lr = lane & 15, lg = lane >> 4;
  const int rw = (w >> 1) * 16;           // row group: 0,16,32,48
  const int cw = (w & 1) * 256;           // col half

  __shared__ float Mcol[Ln];
  __shared__ float gcol[Ln];
  __shared__ float redsum[2][64];
  __shared__ float wred[8];

  for (int j = tid; j < Ln; j += 512) {
    Mcol[j] = mask[b * Ln + j];
    gcol[j] = 0.0f;
  }
  __syncthreads();

  const size_t hb = (size_t)(b * NHn + h) * Ln;
  const unsigned short* pas = sbf + (hb + i0 + rw + lr) * DHn + lg * 8;
  const unsigned short* pat = tbf + (hb + i0 + rw + lr) * DHn + lg * 8;
  bf16x8 sa0 = *(const bf16x8*)pas;
  bf16x8 sa1 = *(const bf16x8*)(pas + 32);
  bf16x8 ta0 = *(const bf16x8*)pat;
  bf16x8 ta1 = *(const bf16x8*)(pat + 32);
  float mrow[4];
  #pragma unroll
  for (int q = 0; q < 4; ++q) mrow[q] = mask[b * Ln + i0 + rw + lg * 4 + q];

  const f32x4 zero4 = {0.0f, 0.0f, 0.0f, 0.0f};
  float lpair = 0.0f;
  float rsum[4] = {0.0f, 0.0f, 0.0f, 0.0f};
  unsigned int epack[32];                  // deferred e values, packed bf16

  #pragma unroll
  for (int ct = 0; ct < 16; ++ct) {
    const int j0 = cw + ct * 16;
    const unsigned short* pbs = sbf + (hb + j0 + lr) * DHn + lg * 8;
    const unsigned short* pbt = tbf + (hb + j0 + lr) * DHn + lg * 8;
    bf16x8 sb0 = *(const bf16x8*)pbs;
    bf16x8 sb1 = *(const bf16x8*)(pbs + 32);
    bf16x8 tb0 = *(const bf16x8*)pbt;
    bf16x8 tb1 = *(const bf16x8*)(pbt + 32);
    f32x4 sacc = __builtin_amdgcn_mfma_f32_16x16x32_bf16(sa0, sb0, zero4, 0, 0, 0);
    sacc = __builtin_amdgcn_mfma_f32_16x16x32_bf16(sa1, sb1, sacc, 0, 0, 0);
    f32x4 tacc = __builtin_amdgcn_mfma_f32_16x16x32_bf16(ta0, tb0, zero4, 0, 0, 0);
    tacc = __builtin_amdgcn_mfma_f32_16x16x32_bf16(ta1, tb1, tacc, 0, 0, 0);
    const float mj = Mcol[j0 + lr];
    float e4[4];
    #pragma unroll
    for (int q = 0; q < 4; ++q) {
      const float mm = mrow[q] * mj;
      const float ss = sacc[q] * 0.125f * mm;
      const float st = tacc[q] * 0.125f * mm;
      const float d = ss - st;
      lpair += d * d;
      const float e = __expf(st + (1.0f - mm) * (-10000.0f));
      rsum[q] += e;
      e4[q] = e;
    }
    epack[ct * 2]     = (unsigned int)f2bf(e4[0]) | ((unsigned int)f2bf(e4[1]) << 16);
    epack[ct * 2 + 1] = (unsigned int)f2bf(e4[2]) | ((unsigned int)f2bf(e4[3]) << 16);
  }

  // row-sum: reduce over the 16 lr lanes, then across the wave pair (col halves)
  #pragma unroll
  for (int o = 1; o < 16; o <<= 1) {
    #pragma unroll
    for (int q = 0; q < 4; ++q) rsum[q] += __shfl_xor(rsum[q], o, 64);
  }
  if (lr == 0) {
    #pragma unroll
    for (int q = 0; q < 4; ++q) redsum[w & 1][rw + lg * 4 + q] = rsum[q];
  }
  __syncthreads();
  float rscale[4];
  #pragma unroll
  for (int q = 0; q < 4; ++q) {
    const int ri = rw + lg * 4 + q;
    rscale[q] = mrow[q] / fmaxf(redsum[0][ri] + redsum[1][ri], 1e-30f);
  }

  // column partial sums of att = e * rscale; fused per-ct cross-lane reduce
  // (no pc[16] array -- keeps peak register pressure under the 128 cap)
  #pragma unroll
  for (int ct = 0; ct < 16; ++ct) {
    const float e0 = __uint_as_float(epack[ct * 2] << 16);
    const float e1 = __uint_as_float(epack[ct * 2] & 0xffff0000u);
    const float e2 = __uint_as_float(epack[ct * 2 + 1] << 16);
    const float e3 = __uint_as_float(epack[ct * 2 + 1] & 0xffff0000u);
    float pc = e0 * rscale[0] + e1 * rscale[1] + e2 * rscale[2] + e3 * rscale[3];
    pc += __shfl_xor(pc, 16, 64);
    pc += __shfl_xor(pc, 32, 64);
    if (lg == 0) atomicAdd(&gcol[cw + ct * 16 + lr], pc);
  }

  // pair-loss partial
  #pragma unroll
  for (int o = 1; o < 64; o <<= 1) lpair += __shfl_xor(lpair, o, 64);
  if (lane == 0) wred[w] = lpair;
  __syncthreads();

  if (tid == 0) {
    float s = 0.0f;
    #pragma unroll
    for (int i = 0; i < 8; ++i) s += wred[i];
    atomicAdd(&acc[0], (double)s);
  }
  {
    const int j = tid;
    if (j < Ln) atomicAdd(&g_score[b * Ln + j], gcol[j] * Mcol[j]);
  }
}

// ---------------------------------------------------------------------------
// top-k over g_score: single-wave register argmax (tie -> lowest index)
// ---------------------------------------------------------------------------
__global__ __launch_bounds__(64) void topk_g_kernel(
    const float* __restrict__ g_score, int* __restrict__ g_top) {
  const int b = blockIdx.x, lane = threadIdx.x;
  float v[8];
  #pragma unroll
  for (int q = 0; q < 8; ++q) v[q] = g_score[b * Ln + q * 64 + lane];
  for (int r = 0; r < K1n; ++r) {
    float bv = v[0]; int bq = 0;
    #pragma unroll
    for (int q = 1; q < 8; ++q) if (v[q] > bv) { bv = v[q]; bq = q; }
    int bj = bq * 64 + lane;
    #pragma unroll
    for (int o = 1; o < 64; o <<= 1) {
      float ov = __shfl_xor(bv, o, 64);
      int oj = __shfl_xor(bj, o, 64);
      if (ov > bv || (ov == bv && oj < bj)) { bv = ov; bj = oj; }
    }
    if (lane == 0) g_top[b * K1n + r] = bj;
    const int wq = bj >> 6, wl = bj & 63;
    #pragma unroll
    for (int q = 0; q < 8; ++q)
      if (q == wq && lane == wl) v[q] = -3.0e38f;
  }
}

// ---------------------------------------------------------------------------
// Kernel B: recompute att rows only for g_top rows; accumulate over h into
// loc_rows[b][i1][j]. One block per (b, h) = 96 blocks.
// ---------------------------------------------------------------------------
__global__ __launch_bounds__(256, 4) void pairB_kernel(
    const unsigned short* __restrict__ tbf, const float* __restrict__ mask,
    const int* __restrict__ g_top, float* __restrict__ loc_rows) {
  const int b = blockIdx.x & 7;
  const int h = blockIdx.x >> 3;
  const int tid = threadIdx.x;
  const int w = tid >> 6, lane = tid & 63;
  const int lr = lane & 15, lg = lane >> 4;
  const int cw = w * 128;

  __shared__ int gidx[32];
  __shared__ float mrow_s[32];
  __shared__ float rscale_s[32];
  __shared__ float redsum[4][32];
  __shared__ float McolB[Ln];
  __shared__ unsigned short es[32][Ln + 8];

  if (tid < 32) {
    const int gi = (tid < K1n) ? g_top[b * K1n + tid] : 0;
    gidx[tid] = gi;
    mrow_s[tid] = (tid < K1n) ? mask[b * Ln + gi] : 0.0f;
  }
  for (int j = tid; j < Ln; j += 256) McolB[j] = mask[b * Ln + j];
  __syncthreads();

  const size_t hb = (size_t)(b * NHn + h) * Ln;
  bf16x8 ta[2][2];
  #pragma unroll
  for (int rt = 0; rt < 2; ++rt) {
    const unsigned short* p = tbf + (hb + gidx[rt * 16 + lr]) * DHn + lg * 8;
    ta[rt][0] = *(const bf16x8*)p;
    ta[rt][1] = *(const bf16x8*)(p + 32);
  }
  const f32x4 zero4 = {0.0f, 0.0f, 0.0f, 0.0f};
  float rsum[2][4] = {{0, 0, 0, 0}, {0, 0, 0, 0}};
  #pragma unroll
  for (int ct = 0; ct < 8; ++ct) {
    const int j0 = cw + ct * 16;
    const unsigned short* pb = tbf + (hb + j0 + lr) * DHn + lg * 8;
    bf16x8 tb0 = *(const bf16x8*)pb;
    bf16x8 tb1 = *(const bf16x8*)(pb + 32);
    const float mj = McolB[j0 + lr];
    #pragma unroll
    for (int rt = 0; rt < 2; ++rt) {
      f32x4 tacc = __builtin_amdgcn_mfma_f32_16x16x32_bf16(ta[rt][0], tb0, zero4, 0, 0, 0);
      tacc = __builtin_amdgcn_mfma_f32_16x16x32_bf16(ta[rt][1], tb1, tacc, 0, 0, 0);
      #pragma unroll
      for (int q = 0; q < 4; ++q) {
        const int ri = rt * 16 + lg * 4 + q;
        const float mm = mrow_s[ri] * mj;
        const float st = tacc[q] * 0.125f * mm;
        const float e = __expf(st + (1.0f - mm) * (-10000.0f));
        rsum[rt][q] += e;
        es[ri][j0 + lr] = f2bf(e);
      }
    }
  }
  #pragma unroll
  for (int o = 1; o < 16; o <<= 1) {
    #pragma unroll
    for (int rt = 0; rt < 2; ++rt)
      #pragma unroll
      for (int q = 0; q < 4; ++q) rsum[rt][q] += __shfl_xor(rsum[rt][q], o, 64);
  }
  if (lr == 0) {
    #pragma unroll
    for (int rt = 0; rt < 2; ++rt)
      #pragma unroll
      for (int q = 0; q < 4; ++q) redsum[w][rt * 16 + lg * 4 + q] = rsum[rt][q];
  }
  __syncthreads();
  if (tid < 32) {
    const float fs = redsum[0][tid] + redsum[1][tid] + redsum[2][tid] + redsum[3][tid];
    rscale_s[tid] = mrow_s[tid] / fmaxf(fs, 1e-30f);
  }
  __syncthreads();
  for (int idx = tid; idx < K1n * Ln; idx += 256) {
    const int ri = idx >> 9, j = idx & (Ln - 1);
    const float e = bf2f(es[ri][j]);
    atomicAdd(&loc_rows[(size_t)(b * K1n + ri) * Ln + j], e * rscale_s[ri] * McolB[j]);
  }
}

// ---------------------------------------------------------------------------
// top-k over loc rows (diagonal zeroed): single-wave register argmax
// ---------------------------------------------------------------------------
__global__ __launch_bounds__(64) void topk_l_kernel(
    const float* __restrict__ loc_rows, const int* __restrict__ g_top,
    int* __restrict__ l_top) {
  const int blk = blockIdx.x, lane = threadIdx.x;
  const int b = blk / K1n, i1 = blk % K1n;
  const int g = g_top[b * K1n + i1];
  const float* r0 = loc_rows + (size_t)(b * K1n + i1) * Ln;
  float v[8];
  #pragma unroll
  for (int q = 0; q < 8; ++q) {
    const int j = q * 64 + lane;
    v[q] = (j == g) ? 0.0f : r0[j];
  }
  for (int r = 0; r < K2n; ++r) {
    float bv = v[0]; int bq = 0;
    #pragma unroll
    for (int q = 1; q < 8; ++q) if (v[q] > bv) { bv = v[q]; bq = q; }
    int bj = bq * 64 + lane;
    #pragma unroll
    for (int o = 1; o < 64; o <<= 1) {
      float ov = __shfl_xor(bv, o, 64);
      int oj = __shfl_xor(bj, o, 64);
      if (ov > bv || (ov == bv && oj < bj)) { bv = ov; bj = oj; }
    }
    if (lane == 0) l_top[(b * K1n + i1) * K2n + r] = bj;
    const int wq = bj >> 6, wl = bj & 63;
    #pragma unroll
    for (int q = 0; q < 8; ++q)
      if (q == wq && lane == wl) v[q] = -3.0e38f;
  }
}

// ---------------------------------------------------------------------------
// Triplet loss: normalized diffs (fp32 math) -> bf16 LDS; 20x20 Gram via MFMA
// (one 16x16 quadrant per wave). One block per (b, i1).
// ---------------------------------------------------------------------------
#define TP (Dn + 16)

__global__ __launch_bounds__(256, 1) void triplet_kernel(
    const float* __restrict__ s_rep, const float* __restrict__ t_rep,
    const float* __restrict__ mask, const int* __restrict__ g_top,
    const int* __restrict__ l_top, double* __restrict__ acc) {
  const int blk = blockIdx.x, tid = threadIdx.x;
  const int b = blk / K1n, i1 = blk % K1n;
  const int w = tid >> 6, lane = tid & 63;
  const int lr = lane & 15, lg = lane >> 4;

  __shared__ unsigned short NS[32][TP];
  __shared__ unsigned short NT[32][TP];
  __shared__ int lidx[K2n];
  __shared__ float fl2[K2n];
  __shared__ float sred[4], cred[4];

  const int g = g_top[b * K1n + i1];
  if (tid < K2n) {
    const int li = l_top[(b * K1n + i1) * K2n + tid];
    lidx[tid] = li;
    fl2[tid] = (mask[b * Ln + g] + mask[b * Ln + li] == 2.0f) ? 1.0f : 0.0f;
  }
  __syncthreads();

  const float* pgs = s_rep + (size_t)(b * Ln + g) * Dn;
  const float* pgt = t_rep + (size_t)(b * Ln + g) * Dn;
  for (int j = w; j < K2n; j += 4) {
    const float* pls = s_rep + (size_t)(b * Ln + lidx[j]) * Dn;
    const float* plt = t_rep + (size_t)(b * Ln + lidx[j]) * Dn;
    float4 ds[3], dt[3];
    float ssq = 0.0f, tsq = 0.0f;
    #pragma unroll
    for (int q = 0; q < 3; ++q) {
      const int c = lane * 4 + q * 256;
      float4 a = *(const float4*)&pgs[c];
      float4 x = *(const float4*)&pls[c];
      ds[q] = make_float4(a.x - x.x, a.y - x.y, a.z - x.z, a.w - x.w);
      ssq += ds[q].x * ds[q].x + ds[q].y * ds[q].y + ds[q].z * ds[q].z + ds[q].w * ds[q].w;
      float4 c2 = *(const float4*)&pgt[c];
      float4 y = *(const float4*)&plt[c];
      dt[q] = make_float4(c2.x - y.x, c2.y - y.y, c2.z - y.z, c2.w - y.w);
      tsq += dt[q].x * dt[q].x + dt[q].y * dt[q].y + dt[q].z * dt[q].z + dt[q].w * dt[q].w;
    }
    #pragma unroll
    for (int o = 1; o < 64; o <<= 1) {
      ssq += __shfl_xor(ssq, o, 64);
      tsq += __shfl_xor(tsq, o, 64);
    }
    const float sinv = 1.0f / fmaxf(sqrtf(ssq), 1e-12f);
    const float tinv = 1.0f / fmaxf(sqrtf(tsq), 1e-12f);
    #pragma unroll
    for (int q = 0; q < 3; ++q) {
      const int c = lane * 4 + q * 256;
      ushort4 us, ut;
      us.x = f2bf(ds[q].x * sinv); us.y = f2bf(ds[q].y * sinv);
      us.z = f2bf(ds[q].z * sinv); us.w = f2bf(ds[q].w * sinv);
      ut.x = f2bf(dt[q].x * tinv); ut.y = f2bf(dt[q].y * tinv);
      ut.z = f2bf(dt[q].z * tinv); ut.w = f2bf(dt[q].w * tinv);
      *(ushort4*)&NS[j][c] = us;
      *(ushort4*)&NT[j][c] = ut;
    }
  }
  __syncthreads();

  // Gram quadrant per wave: rows qr*16.., cols qc*16..
  const int qr = w >> 1, qc = w & 1;
  f32x4 sacc = {0.0f, 0.0f, 0.0f, 0.0f};
  f32x4 tacc = {0.0f, 0.0f, 0.0f, 0.0f};
  #pragma unroll
  for (int ks = 0; ks < 24; ++ks) {
    const int kk = ks * 32 + lg * 8;
    bf16x8 as = *(const bf16x8*)&NS[qr * 16 + lr][kk];
    bf16x8 bs = *(const bf16x8*)&NS[qc * 16 + lr][kk];
    bf16x8 at = *(const bf16x8*)&NT[qr * 16 + lr][kk];
    bf16x8 bt = *(const bf16x8*)&NT[qc * 16 + lr][kk];
    sacc = __builtin_amdgcn_mfma_f32_16x16x32_bf16(as, bs, sacc, 0, 0, 0);
    tacc = __builtin_amdgcn_mfma_f32_16x16x32_bf16(at, bt, tacc, 0, 0, 0);
  }
  float psum = 0.0f, pcnt = 0.0f;
  #pragma unroll
  for (int q = 0; q < 4; ++q) {
    const int j2 = qr * 16 + lg * 4 + q;    // Gram row
    const int k2 = qc * 16 + lr;            // Gram col
    if (j2 < K2n && k2 < K2n && j2 != k2) {
      const float am = fl2[j2] * fl2[k2];
      const bool smv = (am != 0.0f) && (sacc[q] != 0.0f);
      const bool tmv = (am != 0.0f) && (tacc[q] != 0.0f);
      const float sv = smv ? sacc[q] : 0.0f;
      const float tv = tmv ? tacc[q] : 0.0f;
      const float d = sv - tv;
      const float ad = fabsf(d);
      psum += (ad < 1.0f) ? 0.5f * d * d : (ad - 0.5f);
      pcnt += smv ? 1.0f : 0.0f;
    }
  }
  #pragma unroll
  for (int o = 1; o < 64; o <<= 1) {
    psum += __shfl_xor(psum, o, 64);
    pcnt += __shfl_xor(pcnt, o, 64);
  }
  if (lane == 0) { sred[w] = psum; cred[w] = pcnt; }
  __syncthreads();
  if (tid == 0) {
    atomicAdd(&acc[1], (double)(sred[0] + sred[1] + sred[2] + sred[3]));
    atomicAdd(&acc[2], (double)(cred[0] + cred[1] + cred[2] + cred[3]));
  }
}

// ---------------------------------------------------------------------------
// Finalize: sum(mext) = sum_b (sum_i m)^2; combine losses.
// ---------------------------------------------------------------------------
__global__ void finalize_kernel(const float* __restrict__ mask,
                                const double* __restrict__ acc, float* __restrict__ out) {
  int tid = threadIdx.x;
  __shared__ float red[4];
  double sm = 0.0;
  for (int b = 0; b < Bn; ++b) {
    float p = 0.0f;
    for (int i = tid; i < Ln; i += 256) p += mask[b * Ln + i];
    #pragma unroll
    for (int o = 1; o < 64; o <<= 1) p += __shfl_xor(p, o, 64);
    __syncthreads();
    if ((tid & 63) == 0) red[tid >> 6] = p;
    __syncthreads();
    if (tid == 0) {
      float rs = red[0] + red[1] + red[2] + red[3];
      sm += (double)rs * (double)rs;
    }
  }
  __syncthreads();
  if (tid == 0) {
    double lp = acc[0] / ((double)NHn * sm);
    double lt = acc[1] / acc[2];
    out[0] = (float)(lp + lt);
  }
}

// ---------------------------------------------------------------------------
extern "C" void kernel_launch(void* const* d_in, const int* in_sizes, int n_in,
                              void* d_out, int out_size, void* d_ws, size_t ws_size,
                              hipStream_t stream) {
  const float* s_rep = (const float*)d_in[0];
  const float* t_rep = (const float*)d_in[1];
  const float* mask  = (const float*)d_in[2];
  float* out = (float*)d_out;

  char* w = (char*)d_ws;
  double* acc      = (double*)(w + WS_ACC);
  float* g_score   = (float*)(w + WS_GSCORE);
  float* loc_rows  = (float*)(w + WS_LOCR);
  int* g_top       = (int*)(w + WS_GTOP);
  int* l_top       = (int*)(w + WS_LTOP);
  unsigned short* sbf = (unsigned short*)(w + WS_SBF);
  unsigned short* tbf = (unsigned short*)(w + WS_TBF);

  hipMemsetAsync(d_ws, 0, WS_ZERO_BYTES, stream);

  prep_bf16_kernel<<<Bn * Ln * Dn / 4 / 256, 256, 0, stream>>>(s_rep, t_rep, sbf, tbf);
  pairA_kernel<<<Bn * NHn * (Ln / 64), 512, 0, stream>>>(sbf, tbf, mask, g_score, acc);
  topk_g_kernel<<<Bn, 64, 0, stream>>>(g_score, g_top);
  pairB_kernel<<<Bn * NHn, 256, 0, stream>>>(tbf, mask, g_top, loc_rows);
  topk_l_kernel<<<Bn * K1n, 64, 0, stream>>>(loc_rows, g_top, l_top);
  triplet_kernel<<<Bn * K1n, 256, 0, stream>>>(s_rep, t_rep, mask, g_top, l_top, acc);
  finalize_kernel<<<1, 256, 0, stream>>>(mask, acc, out);
}

// Round 6
// 147.485 us; speedup vs baseline: 2.1528x; 1.3243x over previous
//
#include <hip/hip_runtime.h>
#include <hip/hip_bf16.h>
#include <math.h>

#define Bn 8
#define Ln 512
#define Dn 768
#define NHn 12
#define DHn 64
#define K1n 20
#define K2n 20

// workspace layout (bytes)
#define WS_ACC    0          // double acc[8]: [0]=pair_num [1]=trip_num [2]=trip_cnt
#define WS_GSCORE 64         // float g_score[8*512]
#define WS_LOCR   16448      // float loc_rows[8*20*512] (320 KB)
#define WS_GTOP   344128     // int g_top[8*20]
#define WS_LTOP   344768     // int l_top[8*20*20]
#define WS_SBF    357568     // ushort sbf[8*12*512*64] bf16 head-major
#define WS_TBF    6649024    // ushort tbf[...] (ends 12940480)
#define WS_ZERO_BYTES 344128 // acc + g_score + loc_rows

typedef __attribute__((ext_vector_type(8))) short bf16x8;
typedef __attribute__((ext_vector_type(4))) float f32x4;

__device__ inline unsigned short f2bf(float x) {
  __hip_bfloat16 h = __float2bfloat16(x);
  return *reinterpret_cast<unsigned short*>(&h);
}
__device__ inline float bf2f(unsigned short u) {
  return __uint_as_float(((unsigned int)u) << 16);
}

// ---------------------------------------------------------------------------
// Prep: fp32 [b][row][h*64+k] -> bf16 head-major [b][h][row][k]
// ---------------------------------------------------------------------------
__global__ __launch_bounds__(256) void prep_bf16_kernel(
    const float* __restrict__ s, const float* __restrict__ t,
    unsigned short* __restrict__ sbf, unsigned short* __restrict__ tbf) {
  int gid = blockIdx.x * 256 + threadIdx.x;
  int f = gid * 4;
  int col = f % Dn;
  int rb = f / Dn;
  int row = rb & (Ln - 1);
  int b = rb >> 9;
  int h = col >> 6;
  int k = col & 63;
  size_t dst = (((size_t)(b * NHn + h) * Ln + row) * DHn + k);
  float4 vs = *(const float4*)(s + f);
  float4 vt = *(const float4*)(t + f);
  ushort4 us, ut;
  us.x = f2bf(vs.x); us.y = f2bf(vs.y); us.z = f2bf(vs.z); us.w = f2bf(vs.w);
  ut.x = f2bf(vt.x); ut.y = f2bf(vt.y); ut.z = f2bf(vt.z); ut.w = f2bf(vt.w);
  *(ushort4*)(sbf + dst) = us;
  *(ushort4*)(tbf + dst) = ut;
}

// ---------------------------------------------------------------------------
// Kernel A (two-pass recompute): one block per (b, h, 64-row tile), 256 thr.
// Each WAVE owns a full 16-row x 512-col strip -> row softmax sums are
// wave-local (no barriers, no epack registers). Pass 1: s+t scores, diff^2,
// exp, row-sums. Pass 2: recompute t-scores+exp (bf16 MFMA is deterministic),
// scale, column sums -> g_score. Live set ~70 VGPRs; NO launch-bounds cap
// (rounds 4/5: 64- and 128-VGPR caps both spilled 100+ MB of scratch).
// ---------------------------------------------------------------------------
__global__ __launch_bounds__(256) void pairA_kernel(
    const unsigned short* __restrict__ sbf, const unsigned short* __restrict__ tbf,
    const float* __restrict__ mask, float* __restrict__ g_score,
    double* __restrict__ acc) {
  const int b = blockIdx.x & 7;
  const int r = blockIdx.x >> 3;          // 0..95
  const int it = r / NHn;                 // 0..7
  const int h = r - it * NHn;             // 0..11
  const int i0 = it * 64;
  const int tid = threadIdx.x;
  const int w = tid >> 6;                 // wave 0..3: rows [i0+w*16, +16)
  const int lane = tid & 63;
  const int lr = lane & 15, lg = lane >> 4;

  __shared__ float Mcol[Ln];
  __shared__ float gcol[Ln];
  __shared__ float wred[4];

  for (int j = tid; j < Ln; j += 256) {
    Mcol[j] = mask[b * Ln + j];
    gcol[j] = 0.0f;
  }
  __syncthreads();

  const size_t hb = (size_t)(b * NHn + h) * Ln;
  const int rw = i0 + w * 16;
  const unsigned short* pas = sbf + (hb + rw + lr) * DHn + lg * 8;
  const unsigned short* pat = tbf + (hb + rw + lr) * DHn + lg * 8;
  bf16x8 sa0 = *(const bf16x8*)pas;
  bf16x8 sa1 = *(const bf16x8*)(pas + 32);
  bf16x8 ta0 = *(const bf16x8*)pat;
  bf16x8 ta1 = *(const bf16x8*)(pat + 32);
  float mrow[4];
  #pragma unroll
  for (int q = 0; q < 4; ++q) mrow[q] = mask[b * Ln + rw + lg * 4 + q];

  const f32x4 zero4 = {0.0f, 0.0f, 0.0f, 0.0f};
  float lpair = 0.0f;
  float rsum[4] = {0.0f, 0.0f, 0.0f, 0.0f};

  // ---- pass 1: diff^2 + unnormalized row sums ----
  for (int ct = 0; ct < 32; ++ct) {
    const int j0 = ct * 16;
    const unsigned short* pbs = sbf + (hb + j0 + lr) * DHn + lg * 8;
    const unsigned short* pbt = tbf + (hb + j0 + lr) * DHn + lg * 8;
    bf16x8 sb0 = *(const bf16x8*)pbs;
    bf16x8 sb1 = *(const bf16x8*)(pbs + 32);
    bf16x8 tb0 = *(const bf16x8*)pbt;
    bf16x8 tb1 = *(const bf16x8*)(pbt + 32);
    f32x4 sacc = __builtin_amdgcn_mfma_f32_16x16x32_bf16(sa0, sb0, zero4, 0, 0, 0);
    sacc = __builtin_amdgcn_mfma_f32_16x16x32_bf16(sa1, sb1, sacc, 0, 0, 0);
    f32x4 tacc = __builtin_amdgcn_mfma_f32_16x16x32_bf16(ta0, tb0, zero4, 0, 0, 0);
    tacc = __builtin_amdgcn_mfma_f32_16x16x32_bf16(ta1, tb1, tacc, 0, 0, 0);
    const float mj = Mcol[j0 + lr];
    #pragma unroll
    for (int q = 0; q < 4; ++q) {
      const float mm = mrow[q] * mj;
      const float ss = sacc[q] * 0.125f * mm;
      const float st = tacc[q] * 0.125f * mm;
      const float d = ss - st;
      lpair += d * d;
      rsum[q] += __expf(st + (1.0f - mm) * (-10000.0f));
    }
  }

  // wave-local row sums: reduce across the 16 lr lanes of each lg group
  #pragma unroll
  for (int o = 1; o < 16; o <<= 1) {
    #pragma unroll
    for (int q = 0; q < 4; ++q) rsum[q] += __shfl_xor(rsum[q], o, 64);
  }
  float rscale[4];
  #pragma unroll
  for (int q = 0; q < 4; ++q)
    rscale[q] = mrow[q] / fmaxf(rsum[q], 1e-30f);

  // ---- pass 2: recompute e, scale, column sums ----
  for (int ct = 0; ct < 32; ++ct) {
    const int j0 = ct * 16;
    const unsigned short* pbt = tbf + (hb + j0 + lr) * DHn + lg * 8;
    bf16x8 tb0 = *(const bf16x8*)pbt;
    bf16x8 tb1 = *(const bf16x8*)(pbt + 32);
    f32x4 tacc = __builtin_amdgcn_mfma_f32_16x16x32_bf16(ta0, tb0, zero4, 0, 0, 0);
    tacc = __builtin_amdgcn_mfma_f32_16x16x32_bf16(ta1, tb1, tacc, 0, 0, 0);
    const float mj = Mcol[j0 + lr];
    float pc = 0.0f;
    #pragma unroll
    for (int q = 0; q < 4; ++q) {
      const float mm = mrow[q] * mj;
      const float st = tacc[q] * 0.125f * mm;
      const float e = __expf(st + (1.0f - mm) * (-10000.0f));
      pc += e * rscale[q];
    }
    pc += __shfl_xor(pc, 16, 64);
    pc += __shfl_xor(pc, 32, 64);
    if (lg == 0) atomicAdd(&gcol[j0 + lr], pc);
  }

  // pair-loss partial
  #pragma unroll
  for (int o = 1; o < 64; o <<= 1) lpair += __shfl_xor(lpair, o, 64);
  if (lane == 0) wred[w] = lpair;
  __syncthreads();

  if (tid == 0) {
    atomicAdd(&acc[0], (double)((wred[0] + wred[1]) + (wred[2] + wred[3])));
  }
  {
    const int j0 = tid, j1 = tid + 256;
    atomicAdd(&g_score[b * Ln + j0], gcol[j0] * Mcol[j0]);
    atomicAdd(&g_score[b * Ln + j1], gcol[j1] * Mcol[j1]);
  }
}

// ---------------------------------------------------------------------------
// top-k over g_score: single-wave register argmax (tie -> lowest index)
// ---------------------------------------------------------------------------
__global__ __launch_bounds__(64) void topk_g_kernel(
    const float* __restrict__ g_score, int* __restrict__ g_top) {
  const int b = blockIdx.x, lane = threadIdx.x;
  float v[8];
  #pragma unroll
  for (int q = 0; q < 8; ++q) v[q] = g_score[b * Ln + q * 64 + lane];
  for (int r = 0; r < K1n; ++r) {
    float bv = v[0]; int bq = 0;
    #pragma unroll
    for (int q = 1; q < 8; ++q) if (v[q] > bv) { bv = v[q]; bq = q; }
    int bj = bq * 64 + lane;
    #pragma unroll
    for (int o = 1; o < 64; o <<= 1) {
      float ov = __shfl_xor(bv, o, 64);
      int oj = __shfl_xor(bj, o, 64);
      if (ov > bv || (ov == bv && oj < bj)) { bv = ov; bj = oj; }
    }
    if (lane == 0) g_top[b * K1n + r] = bj;
    const int wq = bj >> 6, wl = bj & 63;
    #pragma unroll
    for (int q = 0; q < 8; ++q)
      if (q == wq && lane == wl) v[q] = -3.0e38f;
  }
}

// ---------------------------------------------------------------------------
// Kernel B: recompute att rows only for g_top rows; accumulate over h into
// loc_rows[b][i1][j]. One block per (b, h) = 96 blocks.
// ---------------------------------------------------------------------------
__global__ __launch_bounds__(256, 4) void pairB_kernel(
    const unsigned short* __restrict__ tbf, const float* __restrict__ mask,
    const int* __restrict__ g_top, float* __restrict__ loc_rows) {
  const int b = blockIdx.x & 7;
  const int h = blockIdx.x >> 3;
  const int tid = threadIdx.x;
  const int w = tid >> 6, lane = tid & 63;
  const int lr = lane & 15, lg = lane >> 4;
  const int cw = w * 128;

  __shared__ int gidx[32];
  __shared__ float mrow_s[32];
  __shared__ float rscale_s[32];
  __shared__ float redsum[4][32];
  __shared__ float McolB[Ln];
  __shared__ unsigned short es[32][Ln + 8];

  if (tid < 32) {
    const int gi = (tid < K1n) ? g_top[b * K1n + tid] : 0;
    gidx[tid] = gi;
    mrow_s[tid] = (tid < K1n) ? mask[b * Ln + gi] : 0.0f;
  }
  for (int j = tid; j < Ln; j += 256) McolB[j] = mask[b * Ln + j];
  __syncthreads();

  const size_t hb = (size_t)(b * NHn + h) * Ln;
  bf16x8 ta[2][2];
  #pragma unroll
  for (int rt = 0; rt < 2; ++rt) {
    const unsigned short* p = tbf + (hb + gidx[rt * 16 + lr]) * DHn + lg * 8;
    ta[rt][0] = *(const bf16x8*)p;
    ta[rt][1] = *(const bf16x8*)(p + 32);
  }
  const f32x4 zero4 = {0.0f, 0.0f, 0.0f, 0.0f};
  float rsum[2][4] = {{0, 0, 0, 0}, {0, 0, 0, 0}};
  #pragma unroll
  for (int ct = 0; ct < 8; ++ct) {
    const int j0 = cw + ct * 16;
    const unsigned short* pb = tbf + (hb + j0 + lr) * DHn + lg * 8;
    bf16x8 tb0 = *(const bf16x8*)pb;
    bf16x8 tb1 = *(const bf16x8*)(pb + 32);
    const float mj = McolB[j0 + lr];
    #pragma unroll
    for (int rt = 0; rt < 2; ++rt) {
      f32x4 tacc = __builtin_amdgcn_mfma_f32_16x16x32_bf16(ta[rt][0], tb0, zero4, 0, 0, 0);
      tacc = __builtin_amdgcn_mfma_f32_16x16x32_bf16(ta[rt][1], tb1, tacc, 0, 0, 0);
      #pragma unroll
      for (int q = 0; q < 4; ++q) {
        const int ri = rt * 16 + lg * 4 + q;
        const float mm = mrow_s[ri] * mj;
        const float st = tacc[q] * 0.125f * mm;
        const float e = __expf(st + (1.0f - mm) * (-10000.0f));
        rsum[rt][q] += e;
        es[ri][j0 + lr] = f2bf(e);
      }
    }
  }
  #pragma unroll
  for (int o = 1; o < 16; o <<= 1) {
    #pragma unroll
    for (int rt = 0; rt < 2; ++rt)
      #pragma unroll
      for (int q = 0; q < 4; ++q) rsum[rt][q] += __shfl_xor(rsum[rt][q], o, 64);
  }
  if (lr == 0) {
    #pragma unroll
    for (int rt = 0; rt < 2; ++rt)
      #pragma unroll
      for (int q = 0; q < 4; ++q) redsum[w][rt * 16 + lg * 4 + q] = rsum[rt][q];
  }
  __syncthreads();
  if (tid < 32) {
    const float fs = redsum[0][tid] + redsum[1][tid] + redsum[2][tid] + redsum[3][tid];
    rscale_s[tid] = mrow_s[tid] / fmaxf(fs, 1e-30f);
  }
  __syncthreads();
  for (int idx = tid; idx < K1n * Ln; idx += 256) {
    const int ri = idx >> 9, j = idx & (Ln - 1);
    const float e = bf2f(es[ri][j]);
    atomicAdd(&loc_rows[(size_t)(b * K1n + ri) * Ln + j], e * rscale_s[ri] * McolB[j]);
  }
}

// ---------------------------------------------------------------------------
// top-k over loc rows (diagonal zeroed): single-wave register argmax
// ---------------------------------------------------------------------------
__global__ __launch_bounds__(64) void topk_l_kernel(
    const float* __restrict__ loc_rows, const int* __restrict__ g_top,
    int* __restrict__ l_top) {
  const int blk = blockIdx.x, lane = threadIdx.x;
  const int b = blk / K1n, i1 = blk % K1n;
  const int g = g_top[b * K1n + i1];
  const float* r0 = loc_rows + (size_t)(b * K1n + i1) * Ln;
  float v[8];
  #pragma unroll
  for (int q = 0; q < 8; ++q) {
    const int j = q * 64 + lane;
    v[q] = (j == g) ? 0.0f : r0[j];
  }
  for (int r = 0; r < K2n; ++r) {
    float bv = v[0]; int bq = 0;
    #pragma unroll
    for (int q = 1; q < 8; ++q) if (v[q] > bv) { bv = v[q]; bq = q; }
    int bj = bq * 64 + lane;
    #pragma unroll
    for (int o = 1; o < 64; o <<= 1) {
      float ov = __shfl_xor(bv, o, 64);
      int oj = __shfl_xor(bj, o, 64);
      if (ov > bv || (ov == bv && oj < bj)) { bv = ov; bj = oj; }
    }
    if (lane == 0) l_top[(b * K1n + i1) * K2n + r] = bj;
    const int wq = bj >> 6, wl = bj & 63;
    #pragma unroll
    for (int q = 0; q < 8; ++q)
      if (q == wq && lane == wl) v[q] = -3.0e38f;
  }
}

// ---------------------------------------------------------------------------
// Triplet loss: normalized diffs (fp32 math) -> bf16 LDS; 20x20 Gram via MFMA
// (one 16x16 quadrant per wave). One block per (b, i1).
// ---------------------------------------------------------------------------
#define TP (Dn + 16)

__global__ __launch_bounds__(256, 1) void triplet_kernel(
    const float* __restrict__ s_rep, const float* __restrict__ t_rep,
    const float* __restrict__ mask, const int* __restrict__ g_top,
    const int* __restrict__ l_top, double* __restrict__ acc) {
  const int blk = blockIdx.x, tid = threadIdx.x;
  const int b = blk / K1n, i1 = blk % K1n;
  const int w = tid >> 6, lane = tid & 63;
  const int lr = lane & 15, lg = lane >> 4;

  __shared__ unsigned short NS[32][TP];
  __shared__ unsigned short NT[32][TP];
  __shared__ int lidx[K2n];
  __shared__ float fl2[K2n];
  __shared__ float sred[4], cred[4];

  const int g = g_top[b * K1n + i1];
  if (tid < K2n) {
    const int li = l_top[(b * K1n + i1) * K2n + tid];
    lidx[tid] = li;
    fl2[tid] = (mask[b * Ln + g] + mask[b * Ln + li] == 2.0f) ? 1.0f : 0.0f;
  }
  __syncthreads();

  const float* pgs = s_rep + (size_t)(b * Ln + g) * Dn;
  const float* pgt = t_rep + (size_t)(b * Ln + g) * Dn;
  for (int j = w; j < K2n; j += 4) {
    const float* pls = s_rep + (size_t)(b * Ln + lidx[j]) * Dn;
    const float* plt = t_rep + (size_t)(b * Ln + lidx[j]) * Dn;
    float4 ds[3], dt[3];
    float ssq = 0.0f, tsq = 0.0f;
    #pragma unroll
    for (int q = 0; q < 3; ++q) {
      const int c = lane * 4 + q * 256;
      float4 a = *(const float4*)&pgs[c];
      float4 x = *(const float4*)&pls[c];
      ds[q] = make_float4(a.x - x.x, a.y - x.y, a.z - x.z, a.w - x.w);
      ssq += ds[q].x * ds[q].x + ds[q].y * ds[q].y + ds[q].z * ds[q].z + ds[q].w * ds[q].w;
      float4 c2 = *(const float4*)&pgt[c];
      float4 y = *(const float4*)&plt[c];
      dt[q] = make_float4(c2.x - y.x, c2.y - y.y, c2.z - y.z, c2.w - y.w);
      tsq += dt[q].x * dt[q].x + dt[q].y * dt[q].y + dt[q].z * dt[q].z + dt[q].w * dt[q].w;
    }
    #pragma unroll
    for (int o = 1; o < 64; o <<= 1) {
      ssq += __shfl_xor(ssq, o, 64);
      tsq += __shfl_xor(tsq, o, 64);
    }
    const float sinv = 1.0f / fmaxf(sqrtf(ssq), 1e-12f);
    const float tinv = 1.0f / fmaxf(sqrtf(tsq), 1e-12f);
    #pragma unroll
    for (int q = 0; q < 3; ++q) {
      const int c = lane * 4 + q * 256;
      ushort4 us, ut;
      us.x = f2bf(ds[q].x * sinv); us.y = f2bf(ds[q].y * sinv);
      us.z = f2bf(ds[q].z * sinv); us.w = f2bf(ds[q].w * sinv);
      ut.x = f2bf(dt[q].x * tinv); ut.y = f2bf(dt[q].y * tinv);
      ut.z = f2bf(dt[q].z * tinv); ut.w = f2bf(dt[q].w * tinv);
      *(ushort4*)&NS[j][c] = us;
      *(ushort4*)&NT[j][c] = ut;
    }
  }
  __syncthreads();

  // Gram quadrant per wave: rows qr*16.., cols qc*16..
  const int qr = w >> 1, qc = w & 1;
  f32x4 sacc = {0.0f, 0.0f, 0.0f, 0.0f};
  f32x4 tacc = {0.0f, 0.0f, 0.0f, 0.0f};
  #pragma unroll
  for (int ks = 0; ks < 24; ++ks) {
    const int kk = ks * 32 + lg * 8;
    bf16x8 as = *(const bf16x8*)&NS[qr * 16 + lr][kk];
    bf16x8 bs = *(const bf16x8*)&NS[qc * 16 + lr][kk];
    bf16x8 at = *(const bf16x8*)&NT[qr * 16 + lr][kk];
    bf16x8 bt = *(const bf16x8*)&NT[qc * 16 + lr][kk];
    sacc = __builtin_amdgcn_mfma_f32_16x16x32_bf16(as, bs, sacc, 0, 0, 0);
    tacc = __builtin_amdgcn_mfma_f32_16x16x32_bf16(at, bt, tacc, 0, 0, 0);
  }
  float psum = 0.0f, pcnt = 0.0f;
  #pragma unroll
  for (int q = 0; q < 4; ++q) {
    const int j2 = qr * 16 + lg * 4 + q;    // Gram row
    const int k2 = qc * 16 + lr;            // Gram col
    if (j2 < K2n && k2 < K2n && j2 != k2) {
      const float am = fl2[j2] * fl2[k2];
      const bool smv = (am != 0.0f) && (sacc[q] != 0.0f);
      const bool tmv = (am != 0.0f) && (tacc[q] != 0.0f);
      const float sv = smv ? sacc[q] : 0.0f;
      const float tv = tmv ? tacc[q] : 0.0f;
      const float d = sv - tv;
      const float ad = fabsf(d);
      psum += (ad < 1.0f) ? 0.5f * d * d : (ad - 0.5f);
      pcnt += smv ? 1.0f : 0.0f;
    }
  }
  #pragma unroll
  for (int o = 1; o < 64; o <<= 1) {
    psum += __shfl_xor(psum, o, 64);
    pcnt += __shfl_xor(pcnt, o, 64);
  }
  if (lane == 0) { sred[w] = psum; cred[w] = pcnt; }
  __syncthreads();
  if (tid == 0) {
    atomicAdd(&acc[1], (double)(sred[0] + sred[1] + sred[2] + sred[3]));
    atomicAdd(&acc[2], (double)(cred[0] + cred[1] + cred[2] + cred[3]));
  }
}

// ---------------------------------------------------------------------------
// Finalize: sum(mext) = sum_b (sum_i m)^2; combine losses.
// ---------------------------------------------------------------------------
__global__ void finalize_kernel(const float* __restrict__ mask,
                                const double* __restrict__ acc, float* __restrict__ out) {
  int tid = threadIdx.x;
  __shared__ float red[4];
  double sm = 0.0;
  for (int b = 0; b < Bn; ++b) {
    float p = 0.0f;
    for (int i = tid; i < Ln; i += 256) p += mask[b * Ln + i];
    #pragma unroll
    for (int o = 1; o < 64; o <<= 1) p += __shfl_xor(p, o, 64);
    __syncthreads();
    if ((tid & 63) == 0) red[tid >> 6] = p;
    __syncthreads();
    if (tid == 0) {
      float rs = red[0] + red[1] + red[2] + red[3];
      sm += (double)rs * (double)rs;
    }
  }
  __syncthreads();
  if (tid == 0) {
    double lp = acc[0] / ((double)NHn * sm);
    double lt = acc[1] / acc[2];
    out[0] = (float)(lp + lt);
  }
}

// ---------------------------------------------------------------------------
extern "C" void kernel_launch(void* const* d_in, const int* in_sizes, int n_in,
                              void* d_out, int out_size, void* d_ws, size_t ws_size,
                              hipStream_t stream) {
  const float* s_rep = (const float*)d_in[0];
  const float* t_rep = (const float*)d_in[1];
  const float* mask  = (const float*)d_in[2];
  float* out = (float*)d_out;

  char* w = (char*)d_ws;
  double* acc      = (double*)(w + WS_ACC);
  float* g_score   = (float*)(w + WS_GSCORE);
  float* loc_rows  = (float*)(w + WS_LOCR);
  int* g_top       = (int*)(w + WS_GTOP);
  int* l_top       = (int*)(w + WS_LTOP);
  unsigned short* sbf = (unsigned short*)(w + WS_SBF);
  unsigned short* tbf = (unsigned short*)(w + WS_TBF);

  hipMemsetAsync(d_ws, 0, WS_ZERO_BYTES, stream);

  prep_bf16_kernel<<<Bn * Ln * Dn / 4 / 256, 256, 0, stream>>>(s_rep, t_rep, sbf, tbf);
  pairA_kernel<<<Bn * NHn * (Ln / 64), 256, 0, stream>>>(sbf, tbf, mask, g_score, acc);
  topk_g_kernel<<<Bn, 64, 0, stream>>>(g_score, g_top);
  pairB_kernel<<<Bn * NHn, 256, 0, stream>>>(tbf, mask, g_top, loc_rows);
  topk_l_kernel<<<Bn * K1n, 64, 0, stream>>>(loc_rows, g_top, l_top);
  triplet_kernel<<<Bn * K1n, 256, 0, stream>>>(s_rep, t_rep, mask, g_top, l_top, acc);
  finalize_kernel<<<1, 256, 0, stream>>>(mask, acc, out);
}